// Round 8
// baseline (767.721 us; speedup 1.0000x reference)
//
#include <hip/hip_runtime.h>

// Sinkhorn divergence, 512 independent 256-point problems, 24 annealing steps.
// Round 10: matrix-per-quarter decomposition. q in {0..3} owns one potential
// (f, g, px, py); each thread computes the FULL 256-col logsumexp for one
// row of one matrix -> no cross-quarter combine, no msh/ssh, prologue and
// log-epilogue distributed across all threads, and double-buffered column
// arrays give ONE barrier per step (24 vs 48).
//   Hb[buf][mat][j] = (H_mat[j], z_j, t_j, 0), mat written by the quarter
//   owning the potential H depends on (wmat = q<2 ? q^1 : q).
//   arg_ij = H[j] + (ci*inv)*z_j + (ti*inv)*t_j   (inv moved to row side)
// Math: online logsumexp, integer-quantized running max (ceilf), ldexp
// rescale — exact identity, as R5.
// NO ext_vector types (R3/R4: scratch demotion).

constexpr int   N       = 256;   // points per cloud
constexpr int   NPROB   = 512;   // B*S*NR
constexpr int   NRDIM   = 64;
constexpr float DT_F    = 0.001f;
constexpr float EPS_MIN = 1e-4f; // BLUR^P
constexpr int   NSTEPS  = 24;
constexpr float LOG2E   = 1.4426950408889634f;
constexpr float LN2     = 0.6931471805599453f;
constexpr int   NT      = 1024;  // threads per block

extern "C" __global__ void __launch_bounds__(NT, 8)
sinkhorn_div_kernel(const float* __restrict__ syn,
                    const float* __restrict__ obs,
                    float* __restrict__ divs)
{
    const int p   = blockIdx.x;          // ((b*S + s)*NR + r)
    const int r   = p & (NRDIM - 1);
    const int bs  = p >> 6;
    const int tid = threadIdx.x;
    const int row = tid & (N - 1);       // row index i
    const int q   = tid >> 8;            // matrix/potential owner 0..3

    __shared__ float4 Hb[2][4][N];       // 32 KB: [buf][mat][col]=(H,z,t,0)
    __shared__ float  redA[64];

    const size_t base = (size_t)bs * N * NRDIM + r;
    const float xi = obs[base + (size_t)row * NRDIM];   // x cloud = obs
    const float yi = syn[base + (size_t)row * NRDIM];   // y cloud = syn

    // ---- block reductions: diameter (max/min) + all-zero mask sums ----
    float hi = fmaxf(xi, yi), lo = fminf(xi, yi);
    float ax = fabsf(xi),     ay = fabsf(yi);
    #pragma unroll
    for (int off = 32; off > 0; off >>= 1) {
        hi  = fmaxf(hi, __shfl_down(hi, off, 64));
        lo  = fminf(lo, __shfl_down(lo, off, 64));
        ax += __shfl_down(ax, off, 64);
        ay += __shfl_down(ay, off, 64);
    }
    const int wave = tid >> 6;           // 0..15
    if ((tid & 63) == 0) {
        redA[wave * 4 + 0] = hi;  redA[wave * 4 + 1] = lo;
        redA[wave * 4 + 2] = ax;  redA[wave * 4 + 3] = ay;
    }
    __syncthreads();
    float vmax = -3.4e38f, vmin = 3.4e38f, sax = 0.0f, say = 0.0f;
    #pragma unroll
    for (int w = 0; w < 16; ++w) {
        vmax = fmaxf(vmax, redA[w * 4 + 0]);
        vmin = fminf(vmin, redA[w * 4 + 1]);
        sax += redA[w * 4 + 2];
        say += redA[w * 4 + 3];
    }

    const float tspread  = 255.0f * DT_F;
    const float diameter = fmaxf(tspread, vmax - vmin);
    float eps_raw = diameter * diameter;              // eps0 = diameter^2

    const float ti    = (float)row * DT_F;
    const bool  isX   = (q == 0) || (q == 2);  // row cloud is x
    const float ci    = isX ? xi : yi;         // row coefficient & z value
    const float selfP = 0.5f * (ti * ti + ci * ci);
    const bool  damped = (q >= 2);             // px/py use damped update
    const int   wmat  = (q < 2) ? (q ^ 1) : q; // matrix fed by my potential
    const float la2   = -8.0f;                 // log2(1/256)

    float pot = 0.0f;

#define EXP2(x) __builtin_amdgcn_exp2f(x)

    for (int step = 0; step < NSTEPS; ++step) {
        const float eps = fmaxf(eps_raw, EPS_MIN);
        const float inv = LOG2E / eps;
        const int   buf = step & 1;

        // ---- prologue: every thread writes one column of its matrix ----
        Hb[buf][wmat][row] = make_float4(fmaf(pot - selfP, inv, la2),
                                         ci, ti, 0.0f);
        __syncthreads();   // the ONLY barrier this step

        const float tii  = ti * inv;
        const float cinv = ci * inv;
        const float4* __restrict__ Hq = &Hb[buf][q][0];

        float mprev = -1e9f, s = 0.0f;
        #pragma unroll 2
        for (int jb = 0; jb < N; jb += 8) {
            const float4 Q0 = Hq[jb + 0];
            const float4 Q1 = Hq[jb + 1];
            const float4 Q2 = Hq[jb + 2];
            const float4 Q3 = Hq[jb + 3];
            const float4 Q4 = Hq[jb + 4];
            const float4 Q5 = Hq[jb + 5];
            const float4 Q6 = Hq[jb + 6];
            const float4 Q7 = Hq[jb + 7];
            const float a0 = fmaf(cinv, Q0.y, fmaf(tii, Q0.z, Q0.x));
            const float a1 = fmaf(cinv, Q1.y, fmaf(tii, Q1.z, Q1.x));
            const float a2 = fmaf(cinv, Q2.y, fmaf(tii, Q2.z, Q2.x));
            const float a3 = fmaf(cinv, Q3.y, fmaf(tii, Q3.z, Q3.x));
            const float a4 = fmaf(cinv, Q4.y, fmaf(tii, Q4.z, Q4.x));
            const float a5 = fmaf(cinv, Q5.y, fmaf(tii, Q5.z, Q5.x));
            const float a6 = fmaf(cinv, Q6.y, fmaf(tii, Q6.z, Q6.x));
            const float a7 = fmaf(cinv, Q7.y, fmaf(tii, Q7.z, Q7.x));
            // 9-leaf max tree in max3-fusable triples; mprev is integer-
            // valued (or -1e9), so ceil after folding it is still exact.
            const float m0t = fmaxf(fmaxf(a0, a1), a2);
            const float m1t = fmaxf(fmaxf(a3, a4), a5);
            const float m2t = fmaxf(fmaxf(a6, a7), mprev);
            const float M   = ceilf(fmaxf(fmaxf(m0t, m1t), m2t));
            const float t =
                ((EXP2(a0 - M) + EXP2(a1 - M)) + (EXP2(a2 - M) + EXP2(a3 - M))) +
                ((EXP2(a4 - M) + EXP2(a5 - M)) + (EXP2(a6 - M) + EXP2(a7 - M)));
            s = ldexpf(s, (int)(mprev - M)) + t;   // integer delta, exact
            mprev = M;
        }

        // ---- epilogue: local softmin finish (1 log per thread) ----
        const float el2 = eps * LN2;
        const float sm  = selfP - el2 * (mprev + __builtin_amdgcn_logf(s));
        pot = damped ? 0.5f * (pot + sm) : sm;

        eps_raw *= 0.25f;
        // no second barrier: next step writes buf^1; the oldest conflicting
        // access to that buffer is separated by this step's barrier.
    }
#undef EXP2

    // ---- divergence: sum_i (f_i + g_i - px_i - py_i) / N ----
    float contrib = (q < 2) ? pot : -pot;
    #pragma unroll
    for (int off = 32; off > 0; off >>= 1)
        contrib += __shfl_down(contrib, off, 64);
    __syncthreads();                      // redA reuse
    if ((tid & 63) == 0) redA[wave] = contrib;
    __syncthreads();
    if (tid == 0) {
        float total = 0.0f;
        #pragma unroll
        for (int w = 0; w < 16; ++w) total += redA[w];
        total *= (1.0f / (float)N);
        const bool masked_out = (sax == 0.0f) && (say == 0.0f);
        divs[p] = masked_out ? 0.0f : total;
    }
}

extern "C" __global__ void __launch_bounds__(256)
reduce_out_kernel(const float* __restrict__ divs, float* __restrict__ out)
{
    const int b   = blockIdx.x;
    const int tid = threadIdx.x;
    __shared__ float red[4];
    float v = divs[b * 256 + tid];        // 256 = S*NR problems per batch
    #pragma unroll
    for (int off = 32; off > 0; off >>= 1)
        v += __shfl_down(v, off, 64);
    if ((tid & 63) == 0) red[tid >> 6] = v;
    __syncthreads();
    if (tid == 0) out[b] = red[0] + red[1] + red[2] + red[3];
}

extern "C" void kernel_launch(void* const* d_in, const int* in_sizes, int n_in,
                              void* d_out, int out_size, void* d_ws, size_t ws_size,
                              hipStream_t stream) {
    const float* syn = (const float*)d_in[0];   // syn_data
    const float* obs = (const float*)d_in[1];   // obs_data
    float* divs = (float*)d_ws;                 // 512 floats scratch

    sinkhorn_div_kernel<<<NPROB, NT, 0, stream>>>(syn, obs, divs);
    reduce_out_kernel<<<2, 256, 0, stream>>>(divs, (float*)d_out);
}

// Round 9
// 589.272 us; speedup vs baseline: 1.3028x; 1.3028x over previous
//
#include <hip/hip_runtime.h>

// Sinkhorn divergence, 512 independent 256-point problems, 24 annealing steps.
// Round 11: pair-per-half, full-row-per-thread decomposition.
//   NT=512. pair = tid>>8: pair A = {xy->f, yy->py} reads ya; pair B =
//   {yx->g, xx->px} reads xa. Each thread sweeps ALL 256 columns computing
//   its TWO matrices per float4 column read (R5's 0.5 b128/elem
//   amortization) -> complete softmins in-thread: NO combine, NO msh/ssh,
//   no serial q0 section. Potentials cross-feed only through the prologue:
//   pair A writes H_yx (f) into xa and H_yy (py) into ya; pair B writes
//   H_xy (g) into ya and H_xx (px) into xa — 2 b32 writes/thread/step.
//   Double-buffered H arrays -> ONE barrier per step (24 total vs 48).
//   launch_bounds(512,4): VGPR cap 128, chunks' 8 loads can stay live.
//   2 blocks/CU = independent barrier groups (de-phased pipe bursts).
// NO ext_vector types (R3/R4: scratch demotion).
//
// Math (log2 domain, identical element path to R5/R8): online logsumexp,
// integer-quantized running max (ceilf), ldexp rescale — exact identity.
//   arg_ij = H[j] + (ti*inv)*t_j + (coef_i*inv)*z_j
//   H[j]   = la2 + (pot_prev[j] - self[j])*inv ,  inv = log2e/eps

constexpr int   N       = 256;   // points per cloud
constexpr int   NPROB   = 512;   // B*S*NR
constexpr int   NRDIM   = 64;
constexpr float DT_F    = 0.001f;
constexpr float EPS_MIN = 1e-4f; // BLUR^P
constexpr int   NSTEPS  = 24;
constexpr float LOG2E   = 1.4426950408889634f;
constexpr float LN2     = 0.6931471805599453f;
constexpr int   NT      = 512;   // threads per block (8 waves)

extern "C" __global__ void __launch_bounds__(NT, 4)
sinkhorn_div_kernel(const float* __restrict__ syn,
                    const float* __restrict__ obs,
                    float* __restrict__ divs)
{
    const int p    = blockIdx.x;         // ((b*S + s)*NR + r)
    const int r    = p & (NRDIM - 1);
    const int bs   = p >> 6;
    const int tid  = threadIdx.x;
    const int row  = tid & (N - 1);      // row index i
    const int pair = tid >> 8;           // 0: A={xy,yy} over ya ; 1: B={yx,xx} over xa

    __shared__ float4 ya4[2][N];         // [buf][col] = (Hxy, Hyy, y_j, t_j)
    __shared__ float4 xa4[2][N];         // [buf][col] = (Hyx, Hxx, x_j, t_j)
    __shared__ float  redA[32];

    float* yaF = (float*)ya4;            // scalar word view: buf*1024 + j*4 + w
    float* xaF = (float*)xa4;

    const size_t base = (size_t)bs * N * NRDIM + r;
    const float xi = obs[base + (size_t)row * NRDIM];   // x cloud = obs
    const float yi = syn[base + (size_t)row * NRDIM];   // y cloud = syn
    const float ti = (float)row * DT_F;

    // ---- one-time init: static column coords into BOTH buffers ----
    if (pair == 0) {
        const float2 w2 = make_float2(yi, ti);
        *(float2*)&yaF[       row * 4 + 2] = w2;
        *(float2*)&yaF[1024 + row * 4 + 2] = w2;
    } else {
        const float2 w2 = make_float2(xi, ti);
        *(float2*)&xaF[       row * 4 + 2] = w2;
        *(float2*)&xaF[1024 + row * 4 + 2] = w2;
    }

    // ---- block reductions: diameter (max/min) + all-zero mask sums ----
    // (rows appear twice across pairs: harmless for max/min and zero-tests)
    float hi = fmaxf(xi, yi), lo = fminf(xi, yi);
    float ax = fabsf(xi),     ay = fabsf(yi);
    #pragma unroll
    for (int off = 32; off > 0; off >>= 1) {
        hi  = fmaxf(hi, __shfl_down(hi, off, 64));
        lo  = fminf(lo, __shfl_down(lo, off, 64));
        ax += __shfl_down(ax, off, 64);
        ay += __shfl_down(ay, off, 64);
    }
    const int wave = tid >> 6;           // 0..7
    if ((tid & 63) == 0) {
        redA[wave * 4 + 0] = hi;  redA[wave * 4 + 1] = lo;
        redA[wave * 4 + 2] = ax;  redA[wave * 4 + 3] = ay;
    }
    __syncthreads();                     // also covers coord init writes
    float vmax = -3.4e38f, vmin = 3.4e38f, sax = 0.0f, say = 0.0f;
    #pragma unroll
    for (int w = 0; w < 8; ++w) {
        vmax = fmaxf(vmax, redA[w * 4 + 0]);
        vmin = fminf(vmin, redA[w * 4 + 1]);
        sax += redA[w * 4 + 2];
        say += redA[w * 4 + 3];
    }

    const float tspread  = 255.0f * DT_F;
    const float diameter = fmaxf(tspread, vmax - vmin);
    float eps_raw = diameter * diameter;              // eps0 = diameter^2

    const float selfx = 0.5f * (ti * ti + xi * xi);
    const float selfy = 0.5f * (ti * ti + yi * yi);
    const float la2   = -8.0f;                        // log2(1/256)

    // pair A: pot1=f (self1=selfx, coef1=xi), pot2=py (self2=selfy, coef2=yi)
    // pair B: pot1=g (self1=selfy, coef1=yi), pot2=px (self2=selfx, coef2=xi)
    const float self1 = (pair == 0) ? selfx : selfy;
    const float self2 = (pair == 0) ? selfy : selfx;
    const float cf1   = (pair == 0) ? xi : yi;
    const float cf2   = (pair == 0) ? yi : xi;

    float pot1 = 0.0f, pot2 = 0.0f;

#define EXP2(x) __builtin_amdgcn_exp2f(x)

    for (int step = 0; step < NSTEPS; ++step) {
        const float eps = fmaxf(eps_raw, EPS_MIN);
        const float inv = LOG2E / eps;
        const int   bo  = (step & 1) * 1024;     // word offset of H buffer

        // ---- prologue: cross-feed my potentials as next H columns ----
        const float h1 = fmaf(pot1 - self1, inv, la2);
        const float h2 = fmaf(pot2 - self2, inv, la2);
        if (pair == 0) {          // f -> Hyx (xa.x) ; py -> Hyy (ya.y)
            xaF[bo + row * 4 + 0] = h1;
            yaF[bo + row * 4 + 1] = h2;
        } else {                  // g -> Hxy (ya.x) ; px -> Hxx (xa.y)
            yaF[bo + row * 4 + 0] = h1;
            xaF[bo + row * 4 + 1] = h2;
        }
        __syncthreads();          // the ONLY barrier this step

        const float tii = ti * inv;
        const float c1  = cf1 * inv;
        const float c2  = cf2 * inv;
        const float4* __restrict__ Hq = (pair == 0) ? &ya4[step & 1][0]
                                                    : &xa4[step & 1][0];

        float m0 = -1e9f, m1 = -1e9f, s0 = 0.0f, s1 = 0.0f;
        #pragma unroll 4
        for (int jb = 0; jb < N; jb += 8) {
            const float4 Q0 = Hq[jb + 0];
            const float4 Q1 = Hq[jb + 1];
            const float4 Q2 = Hq[jb + 2];
            const float4 Q3 = Hq[jb + 3];
            const float4 Q4 = Hq[jb + 4];
            const float4 Q5 = Hq[jb + 5];
            const float4 Q6 = Hq[jb + 6];
            const float4 Q7 = Hq[jb + 7];
            const float b0 = fmaf(c1, Q0.z, fmaf(tii, Q0.w, Q0.x));
            const float c0_ = fmaf(c2, Q0.z, fmaf(tii, Q0.w, Q0.y));
            const float b1 = fmaf(c1, Q1.z, fmaf(tii, Q1.w, Q1.x));
            const float c1_ = fmaf(c2, Q1.z, fmaf(tii, Q1.w, Q1.y));
            const float b2 = fmaf(c1, Q2.z, fmaf(tii, Q2.w, Q2.x));
            const float c2_ = fmaf(c2, Q2.z, fmaf(tii, Q2.w, Q2.y));
            const float b3 = fmaf(c1, Q3.z, fmaf(tii, Q3.w, Q3.x));
            const float c3_ = fmaf(c2, Q3.z, fmaf(tii, Q3.w, Q3.y));
            const float b4 = fmaf(c1, Q4.z, fmaf(tii, Q4.w, Q4.x));
            const float c4_ = fmaf(c2, Q4.z, fmaf(tii, Q4.w, Q4.y));
            const float b5 = fmaf(c1, Q5.z, fmaf(tii, Q5.w, Q5.x));
            const float c5_ = fmaf(c2, Q5.z, fmaf(tii, Q5.w, Q5.y));
            const float b6 = fmaf(c1, Q6.z, fmaf(tii, Q6.w, Q6.x));
            const float c6_ = fmaf(c2, Q6.z, fmaf(tii, Q6.w, Q6.y));
            const float b7 = fmaf(c1, Q7.z, fmaf(tii, Q7.w, Q7.x));
            const float c7_ = fmaf(c2, Q7.z, fmaf(tii, Q7.w, Q7.y));
            // 9-leaf max trees; m0/m1 integer-valued (or -1e9), ceil-safe
            const float bt0 = fmaxf(fmaxf(b0, b1), b2);
            const float bt1 = fmaxf(fmaxf(b3, b4), b5);
            const float bt2 = fmaxf(fmaxf(b6, b7), m0);
            const float M0  = ceilf(fmaxf(fmaxf(bt0, bt1), bt2));
            const float ct0 = fmaxf(fmaxf(c0_, c1_), c2_);
            const float ct1 = fmaxf(fmaxf(c3_, c4_), c5_);
            const float ct2 = fmaxf(fmaxf(c6_, c7_), m1);
            const float M1  = ceilf(fmaxf(fmaxf(ct0, ct1), ct2));
            const float t0 =
                ((EXP2(b0 - M0) + EXP2(b1 - M0)) + (EXP2(b2 - M0) + EXP2(b3 - M0))) +
                ((EXP2(b4 - M0) + EXP2(b5 - M0)) + (EXP2(b6 - M0) + EXP2(b7 - M0)));
            const float t1 =
                ((EXP2(c0_ - M1) + EXP2(c1_ - M1)) + (EXP2(c2_ - M1) + EXP2(c3_ - M1))) +
                ((EXP2(c4_ - M1) + EXP2(c5_ - M1)) + (EXP2(c6_ - M1) + EXP2(c7_ - M1)));
            s0 = ldexpf(s0, (int)(m0 - M0)) + t0;  m0 = M0;   // integer delta
            s1 = ldexpf(s1, (int)(m1 - M1)) + t1;  m1 = M1;
        }

        // ---- epilogue: thread-local softmin finish (2 logs) ----
        const float el2 = eps * LN2;
        pot1 = self1 - el2 * (m0 + __builtin_amdgcn_logf(s0));                  // f / g
        pot2 = 0.5f * (pot2 + (self2 - el2 * (m1 + __builtin_amdgcn_logf(s1)))); // py / px

        eps_raw *= 0.25f;
        // next prologue writes buf^1; this step's reads of buf are separated
        // from the NEXT reuse of buf (step+2's prologue) by step+1's barrier.
    }
#undef EXP2

    // ---- divergence: pair A holds (f - py), pair B holds (g - px) ----
    float contrib = pot1 - pot2;
    #pragma unroll
    for (int off = 32; off > 0; off >>= 1)
        contrib += __shfl_down(contrib, off, 64);
    __syncthreads();                      // redA reuse
    if ((tid & 63) == 0) redA[wave] = contrib;
    __syncthreads();
    if (tid == 0) {
        float total = 0.0f;
        #pragma unroll
        for (int w = 0; w < 8; ++w) total += redA[w];
        total *= (1.0f / (float)N);
        const bool masked_out = (sax == 0.0f) && (say == 0.0f);
        divs[p] = masked_out ? 0.0f : total;
    }
}

extern "C" __global__ void __launch_bounds__(256)
reduce_out_kernel(const float* __restrict__ divs, float* __restrict__ out)
{
    const int b   = blockIdx.x;
    const int tid = threadIdx.x;
    __shared__ float red[4];
    float v = divs[b * 256 + tid];        // 256 = S*NR problems per batch
    #pragma unroll
    for (int off = 32; off > 0; off >>= 1)
        v += __shfl_down(v, off, 64);
    if ((tid & 63) == 0) red[tid >> 6] = v;
    __syncthreads();
    if (tid == 0) out[b] = red[0] + red[1] + red[2] + red[3];
}

extern "C" void kernel_launch(void* const* d_in, const int* in_sizes, int n_in,
                              void* d_out, int out_size, void* d_ws, size_t ws_size,
                              hipStream_t stream) {
    const float* syn = (const float*)d_in[0];   // syn_data
    const float* obs = (const float*)d_in[1];   // obs_data
    float* divs = (float*)d_ws;                 // 512 floats scratch

    sinkhorn_div_kernel<<<NPROB, NT, 0, stream>>>(syn, obs, divs);
    reduce_out_kernel<<<2, 256, 0, stream>>>(divs, (float*)d_out);
}